// Round 3
// baseline (687.938 us; speedup 1.0000x reference)
//
#include <hip/hip_runtime.h>
#include <hip/hip_bf16.h>

// Shapes (fixed by reference): B=32, T=2048, H=1024, U=1024.
// out = [context (32*1024)][attention_weights (32*2048)]  (fp32)
// V_b is a uniform score shift -> cancels in softmax -> unused.
//
// R3 key change: score = sum_u tanh(pre_u)*Vw_u is ADDITIVE over u, so the
// GEMM splits U into halves across blockIdx.y -> per-wave tile 64Mx64N ->
// acc[4][4]=64 regs -> <=128 total -> 2 blocks/CU (was 1) -> barrier drain
// overlapped by the co-resident block.

#define B_DIM 32
#define T_DIM 2048
#define H_DIM 1024
#define U_DIM 1024

typedef __bf16 bf16x8 __attribute__((ext_vector_type(8)));
typedef float f32x4 __attribute__((ext_vector_type(4)));

__device__ __forceinline__ unsigned int f2bf(float f) {
    unsigned int u = __float_as_uint(f);
    return (u + 0x7FFFu + ((u >> 16) & 1u)) >> 16;   // RNE
}

__device__ __forceinline__ float fast_tanh(float x) {
    x = fminf(9.f, fmaxf(-9.f, x));
    float e = __expf(2.f * x);
    return 1.f - 2.f * __frcp_rn(e + 1.f);
}

// ---------- pass 0a: Wv (first H cols of W_w rows) -> bf16 ----------
__global__ void prep_wv_kernel(const float* __restrict__ W_w,
                               unsigned short* __restrict__ wv) {
    int u = blockIdx.x;            // 1024
    int tid = threadIdx.x;         // 256
    float4 x = reinterpret_cast<const float4*>(W_w + (size_t)u * 2 * H_DIM)[tid];
    uint2 p;
    p.x = f2bf(x.x) | (f2bf(x.y) << 16);
    p.y = f2bf(x.z) | (f2bf(x.w) << 16);
    reinterpret_cast<uint2*>(wv)[(size_t)u * (H_DIM / 4) + tid] = p;
}

// ---------- pass 0b: c[b][u] = q[b] . Wq[u] + W_b[u]  (fp32 exact) ----------
__global__ void prep_c_kernel(const float* __restrict__ q,     // [B][H]
                              const float* __restrict__ W_w,   // [U][2H]
                              const float* __restrict__ W_b,   // [U]
                              float* __restrict__ cvec) {      // [B][U]
    __shared__ float4 q_sh[H_DIM / 4];
    int b = blockIdx.y;
    int u0 = blockIdx.x * 64;
    int tid = threadIdx.x;
    int lane = tid & 63, w = tid >> 6;
    q_sh[tid] = reinterpret_cast<const float4*>(q + (size_t)b * H_DIM)[tid];
    __syncthreads();
#pragma unroll
    for (int i = 0; i < 16; i++) {
        int u = u0 + w * 16 + i;
        const float4* wr = reinterpret_cast<const float4*>(W_w + (size_t)u * 2 * H_DIM + H_DIM);
        float s = 0.f;
#pragma unroll
        for (int j = 0; j < 4; j++) {
            float4 wv4 = wr[j * 64 + lane];
            float4 q4 = q_sh[j * 64 + lane];
            s += wv4.x * q4.x + wv4.y * q4.y + wv4.z * q4.z + wv4.w * q4.w;
        }
#pragma unroll
        for (int off = 32; off >= 1; off >>= 1) s += __shfl_xor(s, off, 64);
        if (lane == 0) cvec[(size_t)b * U_DIM + u] = s + W_b[u];
    }
}

// ---------- pass 1: GEMM(values, Wv^T) + tanh + dot(V_w) -> partial score ----
// grid (1024 m-tiles, 2 u-halves), 512 threads = 8 waves.
// Wave w: n-slice [uh*512 + w*64, +64). acc[4][4] = 64 regs -> 2 blocks/CU.
__global__ __launch_bounds__(512, 4)
void gemm_score_kernel(const float* __restrict__ values,        // [B*T][H]
                       const unsigned short* __restrict__ wv,   // bf16 [U][H]
                       const float* __restrict__ cvec,          // [B][U]
                       const float* __restrict__ Vw,            // [U]
                       float* __restrict__ score_part) {        // [2][B][T]
    __shared__ __align__(16) unsigned short a_sh[2][64 * 72];   // stride 72: 2-way alias only
    __shared__ float sc_sh[64 * 8];

    const int tid = threadIdx.x;
    const int lane = tid & 63;
    const int w = tid >> 6;          // wave 0..7
    const int col = lane & 15;
    const int quad = lane >> 4;
    const int m0 = blockIdx.x * 64;
    const int uh = blockIdx.y;       // u-half
    const int b = m0 >> 11;
    const int t0 = m0 & (T_DIM - 1);

    f32x4 acc[4][4];
    const f32x4 zero4 = {0.f, 0.f, 0.f, 0.f};
#pragma unroll
    for (int mt = 0; mt < 4; mt++)
#pragma unroll
        for (int nt = 0; nt < 4; nt++) acc[mt][nt] = zero4;

    // A staging: thread -> (row = tid>>3, kgroup = tid&7, 8 k each)
    const int srow = tid >> 3;
    const int skg = tid & 7;
    const float* aptr = values + (size_t)(m0 + srow) * H_DIM + skg * 8;
    const int sidx = srow * 72 + skg * 8;

    {   // prologue: stage tile 0
        float4 n0 = reinterpret_cast<const float4*>(aptr)[0];
        float4 n1 = reinterpret_cast<const float4*>(aptr)[1];
        uint4 pk;
        pk.x = f2bf(n0.x) | (f2bf(n0.y) << 16);
        pk.y = f2bf(n0.z) | (f2bf(n0.w) << 16);
        pk.z = f2bf(n1.x) | (f2bf(n1.y) << 16);
        pk.w = f2bf(n1.z) | (f2bf(n1.w) << 16);
        *reinterpret_cast<uint4*>(&a_sh[0][sidx]) = pk;
    }
    __syncthreads();

    const unsigned short* bbase = wv + (size_t)(uh * 512 + w * 64 + col) * H_DIM + quad * 8;

    for (int ks = 0; ks < 16; ks++) {
        const int cur = ks & 1;

        // A prefetch for next K-step (issued first, consumed after all MFMAs)
        float4 n0, n1;
        if (ks < 15) {
            const float* ap = aptr + (ks + 1) * 64;
            n0 = reinterpret_cast<const float4*>(ap)[0];
            n1 = reinterpret_cast<const float4*>(ap)[1];
        }

#pragma unroll
        for (int kk = 0; kk < 2; kk++) {
            bf16x8 bf[4];
#pragma unroll
            for (int nt = 0; nt < 4; nt++)
                bf[nt] = *reinterpret_cast<const bf16x8*>(
                    bbase + (size_t)nt * 16 * H_DIM + ks * 64 + kk * 32);
            bf16x8 af[4];
#pragma unroll
            for (int mt = 0; mt < 4; mt++)
                af[mt] = *reinterpret_cast<const bf16x8*>(
                    &a_sh[cur][(mt * 16 + col) * 72 + kk * 32 + quad * 8]);
#pragma unroll
            for (int nt = 0; nt < 4; nt++)
#pragma unroll
                for (int mt = 0; mt < 4; mt++)
                    acc[mt][nt] = __builtin_amdgcn_mfma_f32_16x16x32_bf16(
                        af[mt], bf[nt], acc[mt][nt], 0, 0, 0);
        }

        if (ks < 15) {
            uint4 pk;
            pk.x = f2bf(n0.x) | (f2bf(n0.y) << 16);
            pk.y = f2bf(n0.z) | (f2bf(n0.w) << 16);
            pk.z = f2bf(n1.x) | (f2bf(n1.y) << 16);
            pk.w = f2bf(n1.z) | (f2bf(n1.w) << 16);
            *reinterpret_cast<uint4*>(&a_sh[1 - cur][sidx]) = pk;
        }
        __syncthreads();
    }

    // ---- epilogue: partial score over this u-half ----
    float cv[4], vwv[4];
#pragma unroll
    for (int nt = 0; nt < 4; nt++) {
        int n = uh * 512 + w * 64 + nt * 16 + col;
        cv[nt] = cvec[(size_t)b * U_DIM + n];
        vwv[nt] = Vw[n];
    }
#pragma unroll
    for (int mt = 0; mt < 4; mt++) {
#pragma unroll
        for (int j = 0; j < 4; j++) {
            float s = 0.f;
#pragma unroll
            for (int nt = 0; nt < 4; nt++)
                s += fast_tanh(acc[mt][nt][j] + cv[nt]) * vwv[nt];
            s += __shfl_xor(s, 1, 64);
            s += __shfl_xor(s, 2, 64);
            s += __shfl_xor(s, 4, 64);
            s += __shfl_xor(s, 8, 64);
            if (col == 0) sc_sh[(mt * 16 + quad * 4 + j) * 8 + w] = s;
        }
    }
    __syncthreads();
    if (tid < 64) {
        float s = 0.f;
#pragma unroll
        for (int ww = 0; ww < 8; ww++) s += sc_sh[tid * 8 + ww];
        score_part[(size_t)uh * (B_DIM * T_DIM) + (size_t)b * T_DIM + t0 + tid] = s;
    }
}

// ---------- pass 2: softmax over T per batch (sums the two u-half partials) --
__global__ void softmax_kernel(const float* __restrict__ score_part,
                               float* __restrict__ aw) {
    int b = blockIdx.x;            // 32
    int tid = threadIdx.x;         // 256
    int lane = tid & 63, w = tid >> 6;
    __shared__ float redm[4];
    __shared__ float reds[4];
    float loc[8];
    float m = -1e30f;
#pragma unroll
    for (int i = 0; i < 8; i++) {
        size_t idx = (size_t)b * T_DIM + tid + i * 256;
        loc[i] = score_part[idx] + score_part[(size_t)(B_DIM * T_DIM) + idx];
        m = fmaxf(m, loc[i]);
    }
#pragma unroll
    for (int off = 32; off >= 1; off >>= 1) m = fmaxf(m, __shfl_xor(m, off, 64));
    if (lane == 0) redm[w] = m;
    __syncthreads();
    m = fmaxf(fmaxf(redm[0], redm[1]), fmaxf(redm[2], redm[3]));
    float sum = 0.f;
#pragma unroll
    for (int i = 0; i < 8; i++) {
        loc[i] = __expf(loc[i] - m);
        sum += loc[i];
    }
#pragma unroll
    for (int off = 32; off >= 1; off >>= 1) sum += __shfl_xor(sum, off, 64);
    if (lane == 0) reds[w] = sum;
    __syncthreads();
    sum = reds[0] + reds[1] + reds[2] + reds[3];
    float inv = 1.0f / sum;
#pragma unroll
    for (int i = 0; i < 8; i++)
        aw[(size_t)b * T_DIM + tid + i * 256] = loc[i] * inv;
}

// ---------- pass 3a: partial context over t-chunks ----------
__global__ void ctx_partial_kernel(const float* __restrict__ values,
                                   const float* __restrict__ aw,
                                   float* __restrict__ partial) {
    int tc = blockIdx.x;           // 16 chunks of 128 t
    int b = blockIdx.y;            // 32
    int tid = threadIdx.x;         // 256 -> h = tid*4..+3
    const float4* v4 = reinterpret_cast<const float4*>(
                           values + ((size_t)b * T_DIM + tc * 128) * H_DIM) + tid;
    const float* a = aw + (size_t)b * T_DIM + tc * 128;
    float4 acc = make_float4(0.f, 0.f, 0.f, 0.f);
#pragma unroll 8
    for (int t = 0; t < 128; t++) {
        float wgt = a[t];
        float4 vv = v4[(size_t)t * (H_DIM / 4)];
        acc.x += wgt * vv.x; acc.y += wgt * vv.y;
        acc.z += wgt * vv.z; acc.w += wgt * vv.w;
    }
    reinterpret_cast<float4*>(partial + ((size_t)b * 16 + tc) * H_DIM)[tid] = acc;
}

// ---------- pass 3b: combine partials ----------
__global__ void ctx_combine_kernel(const float* __restrict__ partial,
                                   float* __restrict__ ctx) {
    int idx = blockIdx.x * 256 + threadIdx.x;   // 32768
    int b = idx >> 10, h = idx & (H_DIM - 1);
    float s = 0.f;
#pragma unroll
    for (int tc = 0; tc < 16; tc++)
        s += partial[((size_t)b * 16 + tc) * H_DIM + h];
    ctx[idx] = s;
}

extern "C" void kernel_launch(void* const* d_in, const int* in_sizes, int n_in,
                              void* d_out, int out_size, void* d_ws, size_t ws_size,
                              hipStream_t stream) {
    const float* query  = (const float*)d_in[0];   // [1][B][H]
    const float* values = (const float*)d_in[1];   // [B][T][H]
    const float* W_w    = (const float*)d_in[2];   // [U][2H]
    const float* W_b    = (const float*)d_in[3];   // [U]
    const float* V_w    = (const float*)d_in[4];   // [1][U]
    // d_in[5] = V_b: uniform score shift, cancels in softmax -> unused.

    float* out = (float*)d_out;
    char* ws = (char*)d_ws;
    float* cvec            = (float*)(ws);                               // 128 KB
    unsigned short* wv     = (unsigned short*)(ws + 131072);             // 2 MB
    float* score_part      = (float*)(ws + 131072 + 2097152);            // 512 KB ([2][B][T])
    float* partial         = (float*)(ws + 131072 + 2097152 + 524288);   // 2 MB
    float* ctx = out;                    // [B][H]
    float* aw  = out + B_DIM * H_DIM;    // [B][T]

    prep_wv_kernel<<<U_DIM, 256, 0, stream>>>(W_w, wv);
    prep_c_kernel<<<dim3(U_DIM / 64, B_DIM), 256, 0, stream>>>(query, W_w, W_b, cvec);
    gemm_score_kernel<<<dim3((B_DIM * T_DIM) / 64, 2), 512, 0, stream>>>(values, wv, cvec, V_w, score_part);
    softmax_kernel<<<B_DIM, 256, 0, stream>>>(score_part, aw);
    ctx_partial_kernel<<<dim3(16, B_DIM), 256, 0, stream>>>(values, aw, partial);
    ctx_combine_kernel<<<128, 256, 0, stream>>>(partial, ctx);
}